// Round 1
// 151.086 us; speedup vs baseline: 1.0948x; 1.0948x over previous
//
#include <hip/hip_runtime.h>
#include <hip/hip_bf16.h>

// BertCRFTagger — B=32, S=512, H=1024, T=32.
//  K0 wpack:      W -> bf16 transposed [t][k]; 8 blocks; b0t0 zeroes out.
//  K1 emis_fused: MFMA GEMV + fused log_softmax, split-K x4.
//                 hidden staged to LDS in A-fragment order as bf16
//                 (coalesced row loads, XOR-swizzled 8B writes = 2-way free;
//                 MFMA loop = 1 ds_read_b128 + 2 L1-hot W loads per kc).
//                 R10: pem dropped — K2 recomputes exp(logem) (bitwise same).
//  K2 chunk:      MFMA chunk transfer matrices; nst from mask ballot.
//                 R10: lgkmcnt-only wait (keeps em prefetch in flight);
//                 stores per-chunk max offset cmax[] for K3.
//  K3 phase2:     one wave/batch: fused numerator + prefetched chunk sweep.
//                 R10: cmax broadcast kills 5-shfl/iter; rescale every 4th
//                 chunk; 4-way split dot accumulators; lgkmcnt-only wait so
//                 next-chunk ecT prefetch stays in flight.

#define Bb 32
#define Ss 512
#define Hh 1024
#define Tt 32
#define NROWS (Bb*Ss)          // 16384
#define NCHUNK 32
#define CHUNK_L 16

typedef __attribute__((ext_vector_type(8))) short bf16x8;
typedef __attribute__((ext_vector_type(4))) float f32x4;

__device__ __forceinline__ short f2bf(float f) {  // RNE fp32->bf16
  union { float f; unsigned u; } v; v.f = f;
  unsigned u = v.u;
  return (short)((u + 0x7FFFu + ((u >> 16) & 1u)) >> 16);
}

// ---------------- K0: pack W -> bf16 [t][k] + zero out ----------------
__global__ __launch_bounds__(128) void wpack_kernel(
    const float* __restrict__ W, short* __restrict__ Wpk,
    float* __restrict__ out) {
  const int k = blockIdx.x * 128 + threadIdx.x;
  if (k == 0) out[0] = 0.f;   // phase2 atomicAdds into this
#pragma unroll
  for (int t = 0; t < 32; ++t)
    Wpk[t * Hh + k] = f2bf(W[k * 32 + t]);
}

// ---------------- K1: fused MFMA emissions + log_softmax, split-K ----------
// grid 1024 x 256thr. Block = rows row0..row0+15; wave wv does K quarter wv.
// A[m=lane&15][k=(lane>>4)*8+j]; B[k][n=lane&15]; C/D col=lane&15,row=q*4+r.
// Stage layout: byte addr = wv*8192 + kc*1024 + (((n*4+q)*16) ^ (kc*32)) + j*2.
__global__ __launch_bounds__(256) void emis_fused_kernel(
    const float* __restrict__ hidden, const short* __restrict__ Wpk,
    const float* __restrict__ bias, float* __restrict__ logem) {
  __shared__ __align__(16) char smem[32768];  // stage (bf16) / red (aliased)
  float* red = (float*)smem;                  // [wave][row][col] stride 33
  const int tid = threadIdx.x;
  const int wv = tid >> 6, lane = tid & 63;
  const int n = lane & 15, q = lane >> 4;
  const int row0 = blockIdx.x * 16;
  const int koff = wv * 256;

  // ---- stage: thread t owns k0=4t of each of the 16 rows ----
  {
    const int swv = tid >> 6;           // k0>>8
    const int skc = (tid >> 3) & 7;     // (k0>>5)&7
    const int sq = (tid >> 1) & 3;      // (k0>>3)&3
    const int sj0 = (tid & 1) * 4;      // k0&7
    const int rbase = swv * 8192 + skc * 1024 + sj0 * 2;
    const int uxor = skc * 32;
    const float* hp = hidden + (size_t)row0 * Hh + 4 * tid;
#pragma unroll
    for (int i = 0; i < 16; ++i) {
      const float4 v = *(const float4*)(hp + (size_t)i * Hh);
      uint2 u;
      u.x = (unsigned short)f2bf(v.x) | ((unsigned)(unsigned short)f2bf(v.y) << 16);
      u.y = (unsigned short)f2bf(v.z) | ((unsigned)(unsigned short)f2bf(v.w) << 16);
      const int unit = ((i * 4 + sq) * 16) ^ uxor;
      *(uint2*)(smem + rbase + unit) = u;  // full addr = swv*8192+skc*1024+unit+sj0*2
    }
  }
  __syncthreads();

  // ---- MFMA loop: 1 ds_read_b128 (A) + 2 global 16B (W) per kc ----
  const short* bpl = Wpk + n * Hh + koff;
  const short* bpr = Wpk + (16 + n) * Hh + koff;
  f32x4 d0 = {0.f, 0.f, 0.f, 0.f}, d1 = {0.f, 0.f, 0.f, 0.f};
#pragma unroll
  for (int kc = 0; kc < 8; ++kc) {
    const int aaddr = wv * 8192 + kc * 1024 + (((n * 4 + q) * 16) ^ (kc * 32));
    const bf16x8 a = *(const bf16x8*)(smem + aaddr);
    const bf16x8 wl = *(const bf16x8*)(bpl + kc * 32 + 8 * q);
    const bf16x8 wr = *(const bf16x8*)(bpr + kc * 32 + 8 * q);
    d0 = __builtin_amdgcn_mfma_f32_16x16x32_bf16(a, wl, d0, 0, 0, 0);
    d1 = __builtin_amdgcn_mfma_f32_16x16x32_bf16(a, wr, d1, 0, 0, 0);
  }
  __syncthreads();  // stage dead -> red may alias

  // partials -> LDS
#pragma unroll
  for (int r = 0; r < 4; ++r) {
    red[(wv * 16 + 4 * q + r) * 33 + n] = d0[r];
    red[(wv * 16 + 4 * q + r) * 33 + 16 + n] = d1[r];
  }
  __syncthreads();

  // combine + softmax: thread = (row = tid>>4, cols c0 = tid&15, c1 = c0+16).
  const int row = tid >> 4, c0 = tid & 15, c1 = 16 + c0;
  float v0 = 0.f, v1 = 0.f;
#pragma unroll
  for (int w = 0; w < 4; ++w) {
    v0 += red[(w * 16 + row) * 33 + c0];
    v1 += red[(w * 16 + row) * 33 + c1];
  }
  const float L0 = v0 + bias[c0], L1 = v1 + bias[c1];
  float mx = fmaxf(L0, L1);
#pragma unroll
  for (int d = 8; d >= 1; d >>= 1) mx = fmaxf(mx, __shfl_xor(mx, d, 16));
  float se = __expf(L0 - mx) + __expf(L1 - mx);
#pragma unroll
  for (int d = 8; d >= 1; d >>= 1) se += __shfl_xor(se, d, 16);
  const float corr = mx + __logf(se);
  const size_t rb = (size_t)(row0 + row) * Tt;
  logem[rb + c0] = L0 - corr;
  logem[rb + c1] = L1 - corr;
}

// ---------------- K2: chunk transfer matrices via MFMA ----------------
__global__ __launch_bounds__(256) void chunk_kernel(
    const float* __restrict__ logem, const float* __restrict__ trans,
    const int* __restrict__ mask, float* __restrict__ ecT,
    float* __restrict__ moff, float* __restrict__ cmax) {
  __shared__ __align__(16) float Pbuf[4 * 32 * 36];
  const int tid = threadIdx.x;
  const int wv = tid >> 6, lane = tid & 63;
  const int n = lane & 15, q = lane >> 4;
  const int chunk = blockIdx.x * 4 + wv;
  const int b = chunk >> 5, cc = chunk & 31;
  float* P = Pbuf + wv * 32 * 36;

  float etr0[8], etr1[8];
#pragma unroll
  for (int jj = 0; jj < 8; ++jj) {
    etr0[jj] = __expf(trans[(8 * q + jj) * 32 + n]);
    etr1[jj] = __expf(trans[(8 * q + jj) * 32 + 16 + n]);
  }

  const int t0 = 1 + cc * CHUNK_L;
  const int rowbase = b * Ss + t0;
  int pred = 0;
  if (lane < 16 && t0 + lane < Ss) pred = mask[rowbase + lane];
  const unsigned long long bal = __ballot(pred != 0);
  const int nst = __popcll(bal & 0xFFFFull);

  bf16x8 a0, a1;
#pragma unroll
  for (int jj = 0; jj < 8; ++jj) {
    a0[jj] = (n == 8 * q + jj) ? (short)0x3F80 : (short)0;
    a1[jj] = (16 + n == 8 * q + jj) ? (short)0x3F80 : (short)0;
  }

  f32x4 d00, d01, d10, d11;
  if (nst == 0) {
#pragma unroll
    for (int r = 0; r < 4; ++r) {
      d00[r] = (4 * q + r == n) ? 1.f : 0.f;
      d01[r] = 0.f;
      d10[r] = 0.f;
      d11[r] = (4 * q + r == n) ? 1.f : 0.f;
    }
  }
  float em0 = 0.f, em1 = 0.f;
  if (nst > 0) {
    em0 = __expf(logem[(size_t)rowbase * Tt + n]);
    em1 = __expf(logem[(size_t)rowbase * Tt + 16 + n]);
  }
  for (int st = 0; st < nst; ++st) {
    float em0n = 0.f, em1n = 0.f;
    if (st + 1 < nst) {
      em0n = __expf(logem[(size_t)(rowbase + st + 1) * Tt + n]);
      em1n = __expf(logem[(size_t)(rowbase + st + 1) * Tt + 16 + n]);
    }
    bf16x8 bL, bR;
#pragma unroll
    for (int jj = 0; jj < 8; ++jj) {
      bL[jj] = f2bf(etr0[jj] * em0);
      bR[jj] = f2bf(etr1[jj] * em1);
    }
    const f32x4 z = {0.f, 0.f, 0.f, 0.f};
    d00 = __builtin_amdgcn_mfma_f32_16x16x32_bf16(a0, bL, z, 0, 0, 0);
    d01 = __builtin_amdgcn_mfma_f32_16x16x32_bf16(a0, bR, z, 0, 0, 0);
    d10 = __builtin_amdgcn_mfma_f32_16x16x32_bf16(a1, bL, z, 0, 0, 0);
    d11 = __builtin_amdgcn_mfma_f32_16x16x32_bf16(a1, bR, z, 0, 0, 0);
    if (st + 1 < nst) {
#pragma unroll
      for (int r = 0; r < 4; ++r) {
        P[(4 * q + r) * 36 + n] = d00[r];
        P[(4 * q + r) * 36 + 16 + n] = d01[r];
        P[(16 + 4 * q + r) * 36 + n] = d10[r];
        P[(16 + 4 * q + r) * 36 + 16 + n] = d11[r];
      }
      asm volatile("s_waitcnt lgkmcnt(0)" ::: "memory");  // LDS roundtrip only;
      __builtin_amdgcn_sched_barrier(0);                  // em prefetch stays in flight
      const float4 lo0 = *(const float4*)&P[n * 36 + 8 * q];
      const float4 lo1 = *(const float4*)&P[n * 36 + 8 * q + 4];
      const float4 hi0 = *(const float4*)&P[(16 + n) * 36 + 8 * q];
      const float4 hi1 = *(const float4*)&P[(16 + n) * 36 + 8 * q + 4];
      a0[0] = f2bf(lo0.x); a0[1] = f2bf(lo0.y); a0[2] = f2bf(lo0.z); a0[3] = f2bf(lo0.w);
      a0[4] = f2bf(lo1.x); a0[5] = f2bf(lo1.y); a0[6] = f2bf(lo1.z); a0[7] = f2bf(lo1.w);
      a1[0] = f2bf(hi0.x); a1[1] = f2bf(hi0.y); a1[2] = f2bf(hi0.z); a1[3] = f2bf(hi0.w);
      a1[4] = f2bf(hi1.x); a1[5] = f2bf(hi1.y); a1[6] = f2bf(hi1.z); a1[7] = f2bf(hi1.w);
    }
    em0 = em0n; em1 = em1n;
  }

  float lg0[4], lg1[4], iv0[4], iv1[4];
#pragma unroll
  for (int r = 0; r < 4; ++r) {
    float m0v = fmaxf(d00[r], d01[r]);
    float m1v = fmaxf(d10[r], d11[r]);
#pragma unroll
    for (int d = 8; d >= 1; d >>= 1) {
      m0v = fmaxf(m0v, __shfl_xor(m0v, d, 16));
      m1v = fmaxf(m1v, __shfl_xor(m1v, d, 16));
    }
    m0v = fmaxf(m0v, 1e-37f);
    m1v = fmaxf(m1v, 1e-37f);
    lg0[r] = __logf(m0v); iv0[r] = __builtin_amdgcn_rcpf(m0v);
    lg1[r] = __logf(m1v); iv1[r] = __builtin_amdgcn_rcpf(m1v);
  }
  float* E = ecT + (size_t)(b * NCHUNK + cc) * 32 * 32;
  {
    float4 s;
    s = make_float4(d00[0] * iv0[0], d00[1] * iv0[1], d00[2] * iv0[2], d00[3] * iv0[3]);
    *(float4*)&E[n * 32 + 4 * q] = s;
    s = make_float4(d10[0] * iv1[0], d10[1] * iv1[1], d10[2] * iv1[2], d10[3] * iv1[3]);
    *(float4*)&E[n * 32 + 16 + 4 * q] = s;
    s = make_float4(d01[0] * iv0[0], d01[1] * iv0[1], d01[2] * iv0[2], d01[3] * iv0[3]);
    *(float4*)&E[(16 + n) * 32 + 4 * q] = s;
    s = make_float4(d11[0] * iv1[0], d11[1] * iv1[1], d11[2] * iv1[2], d11[3] * iv1[3]);
    *(float4*)&E[(16 + n) * 32 + 16 + 4 * q] = s;
  }
  if (n == 0) {
    float* Mo = moff + (size_t)(b * NCHUNK + cc) * 32;
    *(float4*)&Mo[4 * q] = make_float4(lg0[0], lg0[1], lg0[2], lg0[3]);
    *(float4*)&Mo[16 + 4 * q] = make_float4(lg1[0], lg1[1], lg1[2], lg1[3]);
  }
  // per-chunk max of moff row -> cmax (saves a 5-shfl reduce per K3 iter)
  {
    float cm = fmaxf(fmaxf(fmaxf(lg0[0], lg0[1]), fmaxf(lg0[2], lg0[3])),
                     fmaxf(fmaxf(lg1[0], lg1[1]), fmaxf(lg1[2], lg1[3])));
    cm = fmaxf(cm, __shfl_xor(cm, 16));
    cm = fmaxf(cm, __shfl_xor(cm, 32));
    if (lane == 0) cmax[b * NCHUNK + cc] = cm;
  }
}

// ---------------- K3: phase-2 sweep + fused numerator, one wave/batch -------
__global__ __launch_bounds__(64) void phase2_kernel(
    const float* __restrict__ logem, const float* __restrict__ start_trans,
    const float* __restrict__ end_trans, const float* __restrict__ ecT,
    const float* __restrict__ moff, const float* __restrict__ cmax,
    const float* __restrict__ trans, const int* __restrict__ tags,
    const int* __restrict__ mask, float* __restrict__ out) {
  const int b = blockIdx.x;
  const int lane = threadIdx.x;
  const int j = lane & 31;
  __shared__ __align__(16) float qlds[32];

  const int base_row = b * Ss;
  int lensum = 0;
  float snum = 0.f;
#pragma unroll
  for (int k = 0; k < 8; ++k) {
    const int ss = lane + 64 * k;
    const int m = mask[base_row + ss];
    lensum += m;
    if (m) {
      const int tg = tags[base_row + ss];
      snum += logem[(size_t)(base_row + ss) * Tt + tg];
      if (ss > 0) snum += trans[tags[base_row + ss - 1] * Tt + tg];
    }
  }
#pragma unroll
  for (int d = 32; d >= 1; d >>= 1) {
    snum += __shfl_xor(snum, d);
    lensum += __shfl_xor(lensum, d);
  }

  const float* base = ecT + (size_t)b * NCHUNK * 32 * 32;
  const float* mbase = moff + (size_t)b * NCHUNK * 32;
  const float cm_l = cmax[b * NCHUNK + j];  // lane j holds chunk j's max offset

  float4 M[8], N[8];
  const float* r0 = base + j * 32;
#pragma unroll
  for (int k = 0; k < 8; ++k) M[k] = *(const float4*)(r0 + 4 * k);
  float mo_cur = mbase[j];

  float al0 = start_trans[j] + logem[(size_t)base_row * Tt + j];
  float m0 = al0;
#pragma unroll
  for (int d = 16; d >= 1; d >>= 1) m0 = fmaxf(m0, __shfl_xor(m0, d, 32));
  float a = __expf(al0 - m0);
  float Mb = m0;
  const float eend = __expf(end_trans[j]);

  float mo_next = 0.f;
  for (int c = 0; c < NCHUNK; ++c) {
    if (c + 1 < NCHUNK) {
      const float* rn = base + ((c + 1) * 32 + j) * 32;
#pragma unroll
      for (int k = 0; k < 8; ++k) N[k] = *(const float4*)(rn + 4 * k);
      mo_next = mbase[(c + 1) * 32 + j];
    }
    const float mom = __shfl(cm_l, c, 32);   // uniform broadcast, no reduce
    const float qv = a * __expf(mo_cur - mom);
    if (lane < 32) qlds[j] = qv;
    asm volatile("s_waitcnt lgkmcnt(0)" ::: "memory");  // LDS only; ecT
    __builtin_amdgcn_sched_barrier(0);                  // prefetch stays in flight
    float s0 = 0.f, s1 = 0.f, s2 = 0.f, s3 = 0.f;       // depth-8 chains
#pragma unroll
    for (int k = 0; k < 8; ++k) {
      const float4 q4 = *(const float4*)(qlds + 4 * k);
      float* sp = (k & 1) ? ((k & 2) ? &s3 : &s1) : ((k & 2) ? &s2 : &s0);
      *sp = fmaf(q4.x, M[k].x, *sp);
      *sp = fmaf(q4.y, M[k].y, *sp);
      *sp = fmaf(q4.z, M[k].z, *sp);
      *sp = fmaf(q4.w, M[k].w, *sp);
    }
    const float s = (s0 + s1) + (s2 + s3);
    Mb += mom;
    if ((c & 3) == 3) {        // rescale every 4th chunk (exact: skipped
      float m = s;             // log(m) factors ride inside a until here)
#pragma unroll
      for (int d = 16; d >= 1; d >>= 1) m = fmaxf(m, __shfl_xor(m, d, 32));
      m = fmaxf(m, 1e-30f);
      a = s * __builtin_amdgcn_rcpf(m);
      Mb += __logf(m);
    } else {
      a = s;
    }
#pragma unroll
    for (int k = 0; k < 8; ++k) M[k] = N[k];
    mo_cur = mo_next;
  }
  float z = a * eend;
#pragma unroll
  for (int d = 16; d >= 1; d >>= 1) z += __shfl_xor(z, d, 32);
  if (lane == 0) {
    const float numfull = snum + start_trans[tags[base_row]] +
                          end_trans[tags[base_row + lensum - 1]];
    const float denom = Mb + __logf(z);
    atomicAdd(out, -(numfull - denom) * (1.0f / 32.0f));
  }
}

extern "C" void kernel_launch(void* const* d_in, const int* in_sizes, int n_in,
                              void* d_out, int out_size, void* d_ws, size_t ws_size,
                              hipStream_t stream) {
  const float* hidden = (const float*)d_in[0];
  const float* W = (const float*)d_in[1];
  const float* bias = (const float*)d_in[2];
  const float* start_trans = (const float*)d_in[3];
  const float* end_trans = (const float*)d_in[4];
  const float* trans = (const float*)d_in[5];
  const int* tags = (const int*)d_in[6];
  const int* mask = (const int*)d_in[7];
  float* out = (float*)d_out;

  float* logem = (float*)d_ws;                        // 2 MB
  float* ecT = logem + (size_t)NROWS * Tt;            // 4 MB
  float* moff = ecT + (size_t)Bb * NCHUNK * 32 * 32;  // 128 KB
  float* cmax = moff + (size_t)Bb * NCHUNK * 32;      // 4 KB
  short* Wpk = (short*)(cmax + (size_t)Bb * NCHUNK);  // 64 KB

  wpack_kernel<<<8, 128, 0, stream>>>(W, Wpk, out);  // also zeroes out
  emis_fused_kernel<<<NROWS / 16, 256, 0, stream>>>(hidden, Wpk, bias, logem);
  chunk_kernel<<<Bb * NCHUNK / 4, 256, 0, stream>>>(logem, trans, mask, ecT, moff, cmax);
  phase2_kernel<<<Bb, 64, 0, stream>>>(logem, start_trans, end_trans, ecT, moff,
                                       cmax, trans, tags, mask, out);
}